// Round 8
// baseline (1923.191 us; speedup 1.0000x reference)
//
#include <hip/hip_runtime.h>

// ---------------------------------------------------------------------------
// BBCU binary SR network, round 19.
// R18 post-mortem: LDS conv_last regressed (occupancy 9.9%, bank conflicts);
// reverted to R17's 20-VGPR form. Body (32 x ~27us dispatches, ~860us) is now
// the dominant cost -> fused PAIRS of body layers with halo recompute:
//   bconv2: 8x8 tile/block; phase1 = layer 2p on 10x10 halo (bits 12x12 from
//   global, residual f in LDS [100][65]); phase2 = layer 2p+1 on interior,
//   writes global f + bits. Math op-for-op identical (integer conv exact,
//   f32 epilogue order unchanged); only redundant halo compute added.
//   32 dispatches -> 16, per-layer HBM traffic halved. LDS ~40KB, 4 blk/CU.
// Tail: up1 batched over samples (Pbat); hr writes V IN-PLACE over U
// (pointwise-safe); conv_last reads U. 35 dispatches total.
// ws: A[0,16) B[16,32)(body pong, dead before up1) Pbat[16,80) U[80,144)
//     bitsA/B[144,145) bits256[145,147) bits512[147,149) wbits[149,..)
//     scales[150,..)
// ---------------------------------------------------------------------------

typedef unsigned long long u64;
typedef unsigned int u32;
typedef unsigned short u16;

__device__ inline float fadd(float a, float b) { return __fadd_rn(a, b); }
__device__ inline float fmul(float a, float b) { return __fmul_rn(a, b); }

// numpy pairwise sum of |p[0..n)| (exact numpy algorithm, f32) — for scale
__device__ float pw_abs_sum(const float* p, int n) {
  if (n <= 8) {
    float s = fabsf(p[0]);
    for (int i = 1; i < n; i++) s = fadd(s, fabsf(p[i]));
    return s;
  }
  if (n <= 128) {
    float r[8];
#pragma unroll
    for (int q = 0; q < 8; q++) r[q] = fabsf(p[q]);
    int i;
    for (i = 8; i + 8 <= n; i += 8)
#pragma unroll
      for (int q = 0; q < 8; q++) r[q] = fadd(r[q], fabsf(p[i + q]));
    float res = fadd(fadd(fadd(r[0], r[1]), fadd(r[2], r[3])),
                     fadd(fadd(r[4], r[5]), fadd(r[6], r[7])));
    for (; i < n; i++) res = fadd(res, fabsf(p[i]));
    return res;
  }
  int n2 = (n / 2) & ~7;
  return fadd(pw_abs_sum(p, n2), pw_abs_sum(p + n2, n - n2));
}

// --- diagnostic ------------------------------------------------------------
__global__ __launch_bounds__(256) void diag_kernel(float* __restrict__ out,
                                                   int n, float tag) {
  int idx = blockIdx.x * 256 + threadIdx.x;
  if (idx < n) out[idx] = (idx == 0) ? tag : 0.f;
}

// --- weight prep: scale (numpy pairwise mean|w|) + 9 x u64 sign bits -------
__global__ __launch_bounds__(64) void binw_pack_kernel(
    const float* __restrict__ w, u64* __restrict__ wbits,
    float* __restrict__ scale, int nch) {
  int ch = blockIdx.x * 64 + threadIdx.x;
  if (ch >= nch) return;
  const float* wc = w + (size_t)ch * 576;
  float S = pw_abs_sum(wc, 576);
  scale[ch] = __fdiv_rn(S, 576.0f);
  u64 b[9] = {0, 0, 0, 0, 0, 0, 0, 0, 0};
  for (int ci = 0; ci < 64; ci++) {
#pragma unroll
    for (int tap = 0; tap < 9; tap++)
      b[tap] |= (u64)(wc[ci * 9 + tap] > 0.0f) << ci;
  }
#pragma unroll
  for (int tap = 0; tap < 9; tap++) wbits[(size_t)ch * 9 + tap] = b[tap];
}

// --- conv_first, batched over samples (blockIdx.y = n) ---------------------
__global__ __launch_bounds__(256) void conv_first_kernel(
    const float* __restrict__ x,      // (4,3,128,128)
    const float* __restrict__ w, const float* __restrict__ b,
    float* __restrict__ out) {        // (4,64,128,128)
  int n = blockIdx.y;
  const float* xn = x + (size_t)n * 49152;
  float* on = out + (size_t)n * 1048576;
  int idx = blockIdx.x * 256 + threadIdx.x;
  int gx = idx & 127;
  int gy = (idx >> 7) & 127;
  int co = idx >> 14;
  const float* wp = w + co * 27;
  float acc = 0.f;
  for (int ky = 0; ky < 3; ky++) {
    int yy = gy + ky - 1;
    if (yy < 0 || yy > 127) continue;
    for (int kx = 0; kx < 3; kx++) {
      int xx = gx + kx - 1;
      if (xx < 0 || xx > 127) continue;
      for (int ci = 0; ci < 3; ci++)
        acc = fmaf(xn[ci * 16384 + yy * 128 + xx],
                   wp[ci * 9 + ky * 3 + kx], acc);
    }
  }
  float wb = fadd(acc, b[co]);
  on[idx] = wb >= 0.f ? wb : fmul(0.1f, wb);
}

// --- pack: 64ch f32 + move -> u64 sign bits per pixel (batched) ------------
__global__ __launch_bounds__(256) void pack_kernel(
    const float* __restrict__ feat, const float* __restrict__ move,
    u64* __restrict__ bits) {
  int n = blockIdx.y;
  const float* f = feat + (size_t)n * 1048576;
  u64* bo = bits + (size_t)n * 16384;
  int pix = blockIdx.x * 256 + threadIdx.x;
  u64 m = 0;
  for (int ci = 0; ci < 64; ci++) {
    float v = fadd(f[ci * 16384 + pix], move[ci]);
    m |= (u64)(v > 0.0f) << ci;
  }
  bo[pix] = m;
}

// --- fused PAIR of body layers (halo recompute) ----------------------------
// Block: 256 thr, 8x8 output tile, z = sample. Phase1: layer u on 10x10
// halo (400 units = 100px x 4 ch-groups, strided); phase2: layer u+1 on
// 8x8 interior (256 units = 64px x 4cg, cg wave-uniform).
__global__ __launch_bounds__(256) void bconv2_kernel(
    const u64* __restrict__ bits_in,   // (4,16384) layer-u acts
    const float* __restrict__ fin,     // (4,64,128,128)
    const u64* __restrict__ wpair,     // (2,64,9)
    const float* __restrict__ scpair,  // (2,64)
    const float* __restrict__ apair, const float* __restrict__ b1pair,
    const float* __restrict__ b2pair,  // (2,64)
    const float* __restrict__ mv1,     // (64) move of layer u+1
    const float* __restrict__ mv2,     // (64) move of layer u+2 (or up1)
    float* __restrict__ fout,          // (4,64,128,128)
    u64* __restrict__ bits_out)        // (4,16384) layer-(u+2) acts
{
  __shared__ u64 s_w[1152];           // both layers' weights
  __shared__ float s_sc[128], s_a[128], s_b1[128], s_b2[128];
  __shared__ float s_m1[64], s_m2[64];
  __shared__ float s_f[100][65];      // residual f on 10x10 halo (pad 65)
  __shared__ u64 s_b0[144];           // layer-u input bits, 12x12
  __shared__ u64 s_bm[100];           // layer-(u+1) input bits, 10x10

  int t = threadIdx.x;
  for (int i = t; i < 1152; i += 256) s_w[i] = wpair[i];
  if (t < 128) {
    s_sc[t] = scpair[t]; s_a[t] = apair[t];
    s_b1[t] = b1pair[t]; s_b2[t] = b2pair[t];
  } else if (t < 192) {
    s_m1[t - 128] = mv1[t - 128];
  } else {
    s_m2[t - 192] = mv2[t - 192];
  }

  int n = blockIdx.z;
  int x0 = blockIdx.x * 8, y0 = blockIdx.y * 8;
  const u64* bin = bits_in + (size_t)n * 16384;
  const float* fi = fin + (size_t)n * 1048576;

  for (int i = t; i < 144; i += 256) {
    int r = i / 12, c = i - r * 12;
    int gy = y0 - 2 + r, gx = x0 - 2 + c;
    s_b0[i] = (gy >= 0 && gy < 128 && gx >= 0 && gx < 128)
                  ? bin[gy * 128 + gx] : 0ULL;
  }
  for (int i = t; i < 6400; i += 256) {
    int ci = i / 100, px = i - ci * 100;
    int r = px / 10, c = px - r * 10;
    int gy = y0 - 1 + r, gx = x0 - 1 + c;
    s_f[px][ci] = (gy >= 0 && gy < 128 && gx >= 0 && gx < 128)
                      ? fi[(size_t)ci * 16384 + gy * 128 + gx] : 0.f;
  }
  __syncthreads();

  // ---- phase 1: layer u on the 10x10 halo ----
  for (int u_ = t; u_ < 400; u_ += 256) {
    int cg = u_ / 100, px = u_ - cg * 100;
    int r = px / 10, c = px - r * 10;
    int gy = y0 - 1 + r, gx = x0 - 1 + c;
    u32 pk = 0;
    if (gy >= 0 && gy < 128 && gx >= 0 && gx < 128) {
      u64 nb[9];
      int vf = 0, nvalid = 0;
#pragma unroll
      for (int dy = 0; dy < 3; dy++)
#pragma unroll
        for (int dx = 0; dx < 3; dx++) {
          int yy = gy + dy - 1, xx = gx + dx - 1;
          int tap = dy * 3 + dx;
          u64 m = 0;
          if (yy >= 0 && yy < 128 && xx >= 0 && xx < 128) {
            m = s_b0[(r + dy) * 12 + (c + dx)];
            vf |= 1 << tap; nvalid++;
          }
          nb[tap] = m;
        }
      bool interior = (vf == 511);
      int base = 64 * nvalid;
#pragma unroll
      for (int j = 0; j < 16; j++) {
        int co = cg * 16 + j;
        int cc = 0;
#pragma unroll
        for (int tap = 0; tap < 9; tap++)
          cc += __popcll(nb[tap] ^ s_w[co * 9 + tap]);
        if (!interior) {
#pragma unroll
          for (int tap = 0; tap < 9; tap++)
            if (!((vf >> tap) & 1)) cc -= __popcll(s_w[co * 9 + tap]);
        }
        int sint = base - 2 * cc;
        float conv = fmul(s_sc[co], (float)sint);
        float t1 = fadd(conv, s_b1[co]);
        float t2 = t1 >= 0.0f ? t1 : fmul(s_a[co], t1);
        float t3 = fadd(t2, s_b2[co]);
        float ov = fadd(t3, s_f[px][co]);
        s_f[px][co] = ov;
        pk |= (u32)(fadd(ov, s_m1[co]) > 0.0f) << j;
      }
    }
    ((u16*)&s_bm[px])[cg] = (u16)pk;
  }
  __syncthreads();

  // ---- phase 2: layer u+1 on the 8x8 interior ----
  {
    int px = t & 63, cg = t >> 6;        // cg wave-uniform
    int r = px >> 3, c = px & 7;
    int gy = y0 + r, gx = x0 + c;
    int hpx = (r + 1) * 10 + (c + 1);
    u64 nb[9];
    int vf = 0, nvalid = 0;
#pragma unroll
    for (int dy = 0; dy < 3; dy++)
#pragma unroll
      for (int dx = 0; dx < 3; dx++) {
        int yy = gy + dy - 1, xx = gx + dx - 1;
        int tap = dy * 3 + dx;
        u64 m = 0;
        if (yy >= 0 && yy < 128 && xx >= 0 && xx < 128) {
          m = s_bm[(r + dy) * 10 + (c + dx)];
          vf |= 1 << tap; nvalid++;
        }
        nb[tap] = m;
      }
    bool interior = (vf == 511);
    int base = 64 * nvalid;
    float* fo = fout + (size_t)n * 1048576;
    int pix = gy * 128 + gx;
    u32 pk = 0;
#pragma unroll
    for (int j = 0; j < 16; j++) {
      int co = cg * 16 + j;
      int cc = 0;
#pragma unroll
      for (int tap = 0; tap < 9; tap++)
        cc += __popcll(nb[tap] ^ s_w[576 + co * 9 + tap]);
      if (!interior) {
#pragma unroll
        for (int tap = 0; tap < 9; tap++)
          if (!((vf >> tap) & 1)) cc -= __popcll(s_w[576 + co * 9 + tap]);
      }
      int sint = base - 2 * cc;
      float conv = fmul(s_sc[64 + co], (float)sint);
      float t1 = fadd(conv, s_b1[64 + co]);
      float t2 = t1 >= 0.0f ? t1 : fmul(s_a[64 + co], t1);
      float t3 = fadd(t2, s_b2[64 + co]);
      float ov = fadd(t3, s_f[hpx][co]);
      fo[(size_t)co * 16384 + pix] = ov;
      pk |= (u32)(fadd(ov, s_m2[co]) > 0.0f) << j;
    }
    ((u16*)(bits_out + (size_t)n * 16384))[pix * 4 + cg] = (u16)pk;
  }
}

// --- binary conv + rprelu + residual (tail layers) -------------------------
// Block: 256 thr = 16x4 pixel tile x 4 co-groups (one wave per co-group).
// Variants:
//  !UPSHUF && !V_NHWC : body form. NCHW res/out, u16 bit-pack.
//  !UPSHUF &&  V_NHWC : hr. NHWC float4 residual; out = NHWC V with leaky
//                       pre-applied; NO bit-pack. (in-place over U safe)
//   UPSHUF            : up1/up2. NHWC float4 out, 4x u16 bit-pack;
//                       RES_NHWC selects residual layout.
template <int H, int W, int COUT, bool UPSHUF, bool RES_NHWC, bool V_NHWC>
__global__ __launch_bounds__(256) void bconv_kernel(
    const u64* __restrict__ bits_in,   // (nz,H*W) packed acts
    const float* __restrict__ feat,    // residual source
    const u64* __restrict__ wbits,     // (COUT,9)
    const float* __restrict__ scale, const float* __restrict__ pa,
    const float* __restrict__ pb1, const float* __restrict__ pb2,
    const float* __restrict__ nmove,   // (64) next layer's move
    float* __restrict__ out,
    u64* __restrict__ bits_out)
{
  constexpr int NCO = COUT / 4;
  constexpr size_t HW = (size_t)H * W;
  __shared__ u64 s_w[COUT * 9];
  __shared__ float s_sc[COUT], s_a[COUT], s_b1[COUT], s_b2[COUT], s_mv[64];

  int t = threadIdx.x;
  for (int i = t; i < COUT * 9; i += 256) s_w[i] = wbits[i];
  for (int i = t; i < COUT; i += 256) {
    s_sc[i] = scale[i]; s_a[i] = pa[i]; s_b1[i] = pb1[i]; s_b2[i] = pb2[i];
  }
  if (t < 64) s_mv[t] = nmove[t];
  __syncthreads();

  int n = blockIdx.z;
  const u64* bin = bits_in + (size_t)n * HW;
  const float* fin = feat + (size_t)n * 64 * HW;
  float* outp = out + (size_t)n * (UPSHUF ? 256 : 64) * HW;
  u64* bop = bits_out ? bits_out + (size_t)n * (UPSHUF ? 4 : 1) * HW
                      : nullptr;

  int px = blockIdx.x * 16 + (t & 15);
  int py = blockIdx.y * 4 + ((t >> 4) & 3);
  int cg = t >> 6;                         // wave-uniform co-group
  int pix = py * W + px;

  u64 nb[9];
  int vf = 0, nvalid = 0;
#pragma unroll
  for (int ky = 0; ky < 3; ky++)
#pragma unroll
    for (int kx = 0; kx < 3; kx++) {
      int yy = py + ky - 1, xx = px + kx - 1;
      int tap = ky * 3 + kx;
      u64 m = 0;
      if (yy >= 0 && yy < H && xx >= 0 && xx < W) {
        m = bin[(size_t)yy * W + xx];
        vf |= 1 << tap; nvalid++;
      }
      nb[tap] = m;
    }
  bool interior = (vf == 511);
  int base = 64 * nvalid;

  if constexpr (!UPSHUF && !V_NHWC) {
    // ---- body form: NCHW, pack; residual loads hoisted ----
    float rv[16];
#pragma unroll
    for (int j = 0; j < 16; j++)
      rv[j] = fin[(size_t)(cg * NCO + j) * HW + pix];
    u32 pk = 0;
#pragma unroll
    for (int jb = 0; jb < NCO; jb += 4) {
#pragma unroll
      for (int s = 0; s < 4; s++) {
        int j = jb + s;
        int co = cg * NCO + j;
        int c = 0;
#pragma unroll
        for (int tap = 0; tap < 9; tap++)
          c += __popcll(nb[tap] ^ s_w[co * 9 + tap]);
        if (!interior) {
#pragma unroll
          for (int tap = 0; tap < 9; tap++)
            if (!((vf >> tap) & 1)) c -= __popcll(s_w[co * 9 + tap]);
        }
        int sint = base - 2 * c;
        float conv = fmul(s_sc[co], (float)sint);
        float t1 = fadd(conv, s_b1[co]);
        float t2 = t1 >= 0.0f ? t1 : fmul(s_a[co], t1);
        float t3 = fadd(t2, s_b2[co]);
        float ov = fadd(t3, rv[j]);
        outp[(size_t)co * HW + pix] = ov;
        pk |= (u32)(fadd(ov, s_mv[co]) > 0.0f) << j;
      }
    }
    ((u16*)bop)[pix * 4 + cg] = (u16)pk;
  } else if constexpr (!UPSHUF && V_NHWC) {
    // ---- hr path: NHWC residual hoisted, NHWC V out with leaky, no pack --
    float4 uv4[4];
#pragma unroll
    for (int q = 0; q < 4; q++)
      uv4[q] = *(const float4*)(fin + (size_t)pix * 64 + cg * NCO + q * 4);
#pragma unroll
    for (int jb = 0; jb < NCO; jb += 4) {
      float us[4] = {uv4[jb >> 2].x, uv4[jb >> 2].y, uv4[jb >> 2].z,
                     uv4[jb >> 2].w};
      float vq[4];
#pragma unroll
      for (int s = 0; s < 4; s++) {
        int co = cg * NCO + jb + s;
        int c = 0;
#pragma unroll
        for (int tap = 0; tap < 9; tap++)
          c += __popcll(nb[tap] ^ s_w[co * 9 + tap]);
        if (!interior) {
#pragma unroll
          for (int tap = 0; tap < 9; tap++)
            if (!((vf >> tap) & 1)) c -= __popcll(s_w[co * 9 + tap]);
        }
        int sint = base - 2 * c;
        float conv = fmul(s_sc[co], (float)sint);
        float t1 = fadd(conv, s_b1[co]);
        float t2 = t1 >= 0.0f ? t1 : fmul(s_a[co], t1);
        float t3 = fadd(t2, s_b2[co]);
        float ov = fadd(t3, us[s]);
        vq[s] = ov >= 0.0f ? ov : fmul(0.1f, ov);      // leaky pre-applied
      }
      float4 v4 = make_float4(vq[0], vq[1], vq[2], vq[3]);
      *(float4*)(outp + (size_t)pix * 64 + cg * NCO + jb) = v4;
    }
  } else {
    // ---- up path: NHWC out. co = cg*64 + j, j = ((ob+k)<<2)|sp ----
    u32 pk[4] = {0, 0, 0, 0};
    for (int ob = 0; ob < 16; ob += 4) {
#pragma unroll
      for (int sp = 0; sp < 4; sp++) {
        float vq[4];
#pragma unroll
        for (int k = 0; k < 4; k++) {
          int j = ((ob + k) << 2) | sp;
          int co = cg * 64 + j;
          int c = 0;
#pragma unroll
          for (int tap = 0; tap < 9; tap++)
            c += __popcll(nb[tap] ^ s_w[co * 9 + tap]);
          if (!interior) {
#pragma unroll
            for (int tap = 0; tap < 9; tap++)
              if (!((vf >> tap) & 1)) c -= __popcll(s_w[co * 9 + tap]);
          }
          int sint = base - 2 * c;
          float conv = fmul(s_sc[co], (float)sint);
          float t1 = fadd(conv, s_b1[co]);
          float t2 = t1 >= 0.0f ? t1 : fmul(s_a[co], t1);
          float t3 = fadd(t2, s_b2[co]);
          float rv = RES_NHWC ? fin[(size_t)pix * 64 + j]
                              : fin[(size_t)j * HW + pix];
          float ov = fadd(t3, rv);
          vq[k] = ov;
          pk[sp] |= (u32)(fadd(ov, s_mv[cg * 16 + ob + k]) > 0.0f)
                    << (ob + k);
        }
        int dr = sp >> 1, dc = sp & 1;
        size_t opix = (size_t)(2 * py + dr) * (2 * W) + (2 * px + dc);
        float4 v4 = make_float4(vq[0], vq[1], vq[2], vq[3]);
        *(float4*)(outp + opix * 64 + cg * 16 + ob) = v4;
      }
    }
#pragma unroll
    for (int sp = 0; sp < 4; sp++) {
      int dr = sp >> 1, dc = sp & 1;
      size_t opix = (size_t)(2 * py + dr) * (2 * W) + (2 * px + dc);
      ((u16*)bop)[opix * 4 + cg] = (u16)pk[sp];
    }
  }
}

// --- conv_last: V NHWC (512*512,64) leaky pre-applied (R17-proven form) ----
__global__ __launch_bounds__(256) void conv_last_kernel(
    const float* __restrict__ V,      // (512*512,64) leaky-applied
    const float* __restrict__ w, const float* __restrict__ b,
    const float* __restrict__ x,      // (3,128,128)
    float* __restrict__ out) {        // (3,512,512)
  int t = threadIdx.x;
  int gx = blockIdx.x * 16 + (t & 15);
  int gy = blockIdx.y * 16 + (t >> 4);
  float acc0 = 0.f, acc1 = 0.f, acc2 = 0.f;
  for (int ky = 0; ky < 3; ky++) {             // (ky,kx,ci), ci fastest
    int yy = gy + ky - 1;
    if (yy < 0 || yy > 511) continue;
    for (int kx = 0; kx < 3; kx++) {
      int xx = gx + kx - 1;
      if (xx < 0 || xx > 511) continue;
      int tap = ky * 3 + kx;
      const float4* vp = (const float4*)(V + ((size_t)(yy << 9) + xx) * 64);
#pragma unroll 4
      for (int c4 = 0; c4 < 16; c4++) {
        float4 v = vp[c4];
        int k = (c4 * 4) * 9 + tap;
        acc0 = fmaf(v.x, w[k], acc0);
        acc1 = fmaf(v.x, w[576 + k], acc1);
        acc2 = fmaf(v.x, w[1152 + k], acc2);
        acc0 = fmaf(v.y, w[k + 9], acc0);
        acc1 = fmaf(v.y, w[576 + k + 9], acc1);
        acc2 = fmaf(v.y, w[1152 + k + 9], acc2);
        acc0 = fmaf(v.z, w[k + 18], acc0);
        acc1 = fmaf(v.z, w[576 + k + 18], acc1);
        acc2 = fmaf(v.z, w[1152 + k + 18], acc2);
        acc0 = fmaf(v.w, w[k + 27], acc0);
        acc1 = fmaf(v.w, w[576 + k + 27], acc1);
        acc2 = fmaf(v.w, w[1152 + k + 27], acc2);
      }
    }
  }
  float o0 = fadd(acc0, b[0]);
  float o1 = fadd(acc1, b[1]);
  float o2 = fadd(acc2, b[2]);
  float sy = (gy + 0.5f) * 0.25f - 0.5f;
  float sx = (gx + 0.5f) * 0.25f - 0.5f;
  int iy0 = (int)floorf(sy);
  int ix0 = (int)floorf(sx);
  float fy = sy - (float)iy0, fx = sx - (float)ix0;
  int y0c = min(max(iy0, 0), 127), y1c = min(max(iy0 + 1, 0), 127);
  int x0c = min(max(ix0, 0), 127), x1c = min(max(ix0 + 1, 0), 127);
  float accs[3] = {o0, o1, o2};
#pragma unroll
  for (int co = 0; co < 3; co++) {
    const float* xp = x + (size_t)co * 16384;
    float c00 = xp[y0c * 128 + x0c], c01 = xp[y0c * 128 + x1c];
    float c10 = xp[y1c * 128 + x0c], c11 = xp[y1c * 128 + x1c];
    float v0, v1;
    if (y1c == y0c) { v0 = fmul(1.f, c00); v1 = fmul(1.f, c01); }
    else {
      v0 = fadd(fmul(1.f - fy, c00), fmul(fy, c10));
      v1 = fadd(fmul(1.f - fy, c01), fmul(fy, c11));
    }
    float base = (x1c == x0c) ? fmul(1.f, v0)
                              : fadd(fmul(1.f - fx, v0), fmul(fx, v1));
    out[((size_t)co << 18) + ((size_t)gy << 9) + gx] = fadd(accs[co], base);
  }
}

extern "C" void kernel_launch(void* const* d_in, const int* in_sizes, int n_in,
                              void* d_out, int out_size, void* d_ws,
                              size_t ws_size, hipStream_t stream) {
  const float* x         = (const float*)d_in[0];
  const float* cf_w      = (const float*)d_in[1];
  const float* cf_b      = (const float*)d_in[2];
  const float* body_move = (const float*)d_in[3];
  const float* body_w    = (const float*)d_in[4];
  const float* body_a    = (const float*)d_in[5];
  const float* body_b1   = (const float*)d_in[6];
  const float* body_b2   = (const float*)d_in[7];
  const float* up1_move  = (const float*)d_in[8];
  const float* up1_w     = (const float*)d_in[9];
  const float* up1_a     = (const float*)d_in[10];
  const float* up1_b1    = (const float*)d_in[11];
  const float* up1_b2    = (const float*)d_in[12];
  const float* up2_move  = (const float*)d_in[13];
  const float* up2_w     = (const float*)d_in[14];
  const float* up2_a     = (const float*)d_in[15];
  const float* up2_b1    = (const float*)d_in[16];
  const float* up2_b2    = (const float*)d_in[17];
  const float* hr_move   = (const float*)d_in[18];
  const float* hr_w      = (const float*)d_in[19];
  const float* hr_a      = (const float*)d_in[20];
  const float* hr_b1     = (const float*)d_in[21];
  const float* hr_b2     = (const float*)d_in[22];
  const float* cl_w      = (const float*)d_in[23];
  const float* cl_b      = (const float*)d_in[24];
  float* out = (float*)d_out;

  const size_t M = 1024 * 1024;
  if (ws_size < 160 * M) {
    diag_kernel<<<(out_size + 255) / 256, 256, 0, stream>>>(
        out, out_size, (float)(ws_size >> 20));
    return;
  }

  char* ws = (char*)d_ws;
  float* A    = (float*)(ws + 0);          // (4,64,128,128) NCHW, 16M
  float* B    = (float*)(ws + 16 * M);     // body pong (dead before up1)
  float* Pbat = (float*)(ws + 16 * M);     // (4,256*256,64) NHWC, 64M
  float* U    = (float*)(ws + 80 * M);     // (512*512,64) NHWC per-sample;
                                           //   hr writes V in-place here
  u64* bitsA   = (u64*)(ws + 144 * M);     // (4,16384) 512K
  u64* bitsB   = (u64*)(ws + 144 * M + 512 * 1024);
  u64* bits256 = (u64*)(ws + 145 * M);     // (4,65536) 2M
  u64* bits512 = (u64*)(ws + 147 * M);     // (512*512) 2M per-sample
  u64* wbits   = (u64*)(ws + 149 * M);     // 2624*9 u64
  float* scales = (float*)(ws + 150 * M);  // 2624 f32

  // weight prep
  binw_pack_kernel<<<32, 64, 0, stream>>>(body_w, wbits, scales, 2048);
  binw_pack_kernel<<<4, 64, 0, stream>>>(up1_w, wbits + (size_t)2048 * 9,
                                         scales + 2048, 256);
  binw_pack_kernel<<<4, 64, 0, stream>>>(up2_w, wbits + (size_t)2304 * 9,
                                         scales + 2304, 256);
  binw_pack_kernel<<<1, 64, 0, stream>>>(hr_w, wbits + (size_t)2560 * 9,
                                         scales + 2560, 64);

  // head (all samples batched)
  conv_first_kernel<<<dim3(4096, 4), 256, 0, stream>>>(x, cf_w, cf_b, A);
  pack_kernel<<<dim3(64, 4), 256, 0, stream>>>(A, body_move, bitsA);

  // body: 16 fused layer-pairs, batched over samples
  float* fin = A;
  float* fout = B;
  u64* bbin = bitsA;
  u64* bbout = bitsB;
  for (int p = 0; p < 16; p++) {
    const float* m1 = body_move + (2 * p + 1) * 64;
    const float* m2 = (p < 15) ? body_move + (2 * p + 2) * 64 : up1_move;
    bconv2_kernel<<<dim3(16, 16, 4), 256, 0, stream>>>(
        bbin, fin, wbits + (size_t)p * 1152, scales + p * 128,
        body_a + p * 128, body_b1 + p * 128, body_b2 + p * 128,
        m1, m2, fout, bbout);
    float* tf = fin; fin = fout; fout = tf;
    u64* tb = bbin; bbin = bbout; bbout = tb;
  }
  // 16 swaps -> body out in A, bits (packed w/ up1_move) in bitsA

  // up1 batched: NCHW res A -> NHWC Pbat; bits (w/ up2_move) in bits256
  bconv_kernel<128, 128, 256, true, false, false>
      <<<dim3(8, 32, 4), 256, 0, stream>>>(
          bitsA, A, wbits + (size_t)2048 * 9, scales + 2048,
          up1_a, up1_b1, up1_b2, up2_move, Pbat, bits256);

  // per sample: up2 -> hr (in-place V over U) -> conv_last
  for (int n = 0; n < 4; n++) {
    // up2: NHWC res P[n] -> NHWC U; bits (w/ hr_move) in bits512
    bconv_kernel<256, 256, 256, true, true, false>
        <<<dim3(16, 64, 1), 256, 0, stream>>>(
            bits256 + (size_t)n * 65536, Pbat + (size_t)n * 4194304,
            wbits + (size_t)2304 * 9, scales + 2304,
            up2_a, up2_b1, up2_b2, hr_move, U, bits512);
    // hr: NHWC U residual -> V NHWC leaky pre-applied, IN-PLACE over U
    bconv_kernel<512, 512, 64, false, true, true>
        <<<dim3(32, 128, 1), 256, 0, stream>>>(
            bits512, U, wbits + (size_t)2560 * 9, scales + 2560,
            hr_a, hr_b1, hr_b2, hr_move, U, nullptr);
    // conv_last + bilinear base (16x16 tiles, float4 NHWC reads)
    conv_last_kernel<<<dim3(32, 32), 256, 0, stream>>>(
        U, cl_w, cl_b, x + (size_t)n * 49152,
        out + (size_t)n * 786432);
  }
}

// Round 9
// 1714.219 us; speedup vs baseline: 1.1219x; 1.1219x over previous
//
#include <hip/hip_runtime.h>

// ---------------------------------------------------------------------------
// BBCU binary SR network, round 20.
// R19 post-mortem: pair fusion neutral (LDS f-staging + halo recompute ate
// the saved traffic) -> reverted to single-layer body dispatches.
// R20 levers (counter-driven):
//   1. Body bconv: 512-thr blocks = 8 waves = 8 co-groups x 8 ch/thread,
//      __launch_bounds__(512,8). Grid-geometry occupancy cap 50% -> 100%,
//      per-thread latency chain halved. Bit-pack u16 -> u8 slices (internal
//      format, layout-consistent). Math op-for-op identical.
//   2. hr bconv widened identically (NCG=8).
//   3. conv_last: bijective XCD swizzle ((bid&7)*128 + bid>>3) -> each XCD
//      owns 4 contiguous tile-rows; halo/L2 working set becomes resident
//      (FETCH 220MB -> ~110MB predicted).
// ws: A[0,16) B[16,32)(body pong, dead before up1) Pbat[16,80) U[80,144)
//     bitsA/B[144,145) bits256[145,147) bits512[147,149) wbits[149,..)
//     scales[150,..)
// ---------------------------------------------------------------------------

typedef unsigned long long u64;
typedef unsigned int u32;
typedef unsigned short u16;
typedef unsigned char u8;

__device__ inline float fadd(float a, float b) { return __fadd_rn(a, b); }
__device__ inline float fmul(float a, float b) { return __fmul_rn(a, b); }

// numpy pairwise sum of |p[0..n)| (exact numpy algorithm, f32) — for scale
__device__ float pw_abs_sum(const float* p, int n) {
  if (n <= 8) {
    float s = fabsf(p[0]);
    for (int i = 1; i < n; i++) s = fadd(s, fabsf(p[i]));
    return s;
  }
  if (n <= 128) {
    float r[8];
#pragma unroll
    for (int q = 0; q < 8; q++) r[q] = fabsf(p[q]);
    int i;
    for (i = 8; i + 8 <= n; i += 8)
#pragma unroll
      for (int q = 0; q < 8; q++) r[q] = fadd(r[q], fabsf(p[i + q]));
    float res = fadd(fadd(fadd(r[0], r[1]), fadd(r[2], r[3])),
                     fadd(fadd(r[4], r[5]), fadd(r[6], r[7])));
    for (; i < n; i++) res = fadd(res, fabsf(p[i]));
    return res;
  }
  int n2 = (n / 2) & ~7;
  return fadd(pw_abs_sum(p, n2), pw_abs_sum(p + n2, n - n2));
}

// --- diagnostic ------------------------------------------------------------
__global__ __launch_bounds__(256) void diag_kernel(float* __restrict__ out,
                                                   int n, float tag) {
  int idx = blockIdx.x * 256 + threadIdx.x;
  if (idx < n) out[idx] = (idx == 0) ? tag : 0.f;
}

// --- weight prep: scale (numpy pairwise mean|w|) + 9 x u64 sign bits -------
__global__ __launch_bounds__(64) void binw_pack_kernel(
    const float* __restrict__ w, u64* __restrict__ wbits,
    float* __restrict__ scale, int nch) {
  int ch = blockIdx.x * 64 + threadIdx.x;
  if (ch >= nch) return;
  const float* wc = w + (size_t)ch * 576;
  float S = pw_abs_sum(wc, 576);
  scale[ch] = __fdiv_rn(S, 576.0f);
  u64 b[9] = {0, 0, 0, 0, 0, 0, 0, 0, 0};
  for (int ci = 0; ci < 64; ci++) {
#pragma unroll
    for (int tap = 0; tap < 9; tap++)
      b[tap] |= (u64)(wc[ci * 9 + tap] > 0.0f) << ci;
  }
#pragma unroll
  for (int tap = 0; tap < 9; tap++) wbits[(size_t)ch * 9 + tap] = b[tap];
}

// --- conv_first, batched over samples (blockIdx.y = n) ---------------------
__global__ __launch_bounds__(256) void conv_first_kernel(
    const float* __restrict__ x,      // (4,3,128,128)
    const float* __restrict__ w, const float* __restrict__ b,
    float* __restrict__ out) {        // (4,64,128,128)
  int n = blockIdx.y;
  const float* xn = x + (size_t)n * 49152;
  float* on = out + (size_t)n * 1048576;
  int idx = blockIdx.x * 256 + threadIdx.x;
  int gx = idx & 127;
  int gy = (idx >> 7) & 127;
  int co = idx >> 14;
  const float* wp = w + co * 27;
  float acc = 0.f;
  for (int ky = 0; ky < 3; ky++) {
    int yy = gy + ky - 1;
    if (yy < 0 || yy > 127) continue;
    for (int kx = 0; kx < 3; kx++) {
      int xx = gx + kx - 1;
      if (xx < 0 || xx > 127) continue;
      for (int ci = 0; ci < 3; ci++)
        acc = fmaf(xn[ci * 16384 + yy * 128 + xx],
                   wp[ci * 9 + ky * 3 + kx], acc);
    }
  }
  float wb = fadd(acc, b[co]);
  on[idx] = wb >= 0.f ? wb : fmul(0.1f, wb);
}

// --- pack: 64ch f32 + move -> u64 sign bits per pixel (batched) ------------
__global__ __launch_bounds__(256) void pack_kernel(
    const float* __restrict__ feat, const float* __restrict__ move,
    u64* __restrict__ bits) {
  int n = blockIdx.y;
  const float* f = feat + (size_t)n * 1048576;
  u64* bo = bits + (size_t)n * 16384;
  int pix = blockIdx.x * 256 + threadIdx.x;
  u64 m = 0;
  for (int ci = 0; ci < 64; ci++) {
    float v = fadd(f[ci * 16384 + pix], move[ci]);
    m |= (u64)(v > 0.0f) << ci;
  }
  bo[pix] = m;
}

// --- binary conv + rprelu + residual ---------------------------------------
// Block: NCG*64 thr = 16x4 pixel tile x NCG co-groups (one wave each).
// Variants:
//  !UPSHUF && !V_NHWC : body. NCHW res/out, u8/u16 bit-pack slices.
//  !UPSHUF &&  V_NHWC : hr. NHWC float4 residual; out = NHWC V with leaky
//                       pre-applied; NO bit-pack. (in-place over U safe)
//   UPSHUF            : up1/up2 (NCG=4). NHWC float4 out, 4x u16 bit-pack;
//                       RES_NHWC selects residual layout.
template <int H, int W, int COUT, bool UPSHUF, bool RES_NHWC, bool V_NHWC,
          int NCG = 4>
__global__ __launch_bounds__(NCG * 64, NCG == 8 ? 8 : 1) void bconv_kernel(
    const u64* __restrict__ bits_in,   // (nz,H*W) packed acts
    const float* __restrict__ feat,    // residual source
    const u64* __restrict__ wbits,     // (COUT,9)
    const float* __restrict__ scale, const float* __restrict__ pa,
    const float* __restrict__ pb1, const float* __restrict__ pb2,
    const float* __restrict__ nmove,   // (64) next layer's move
    float* __restrict__ out,
    u64* __restrict__ bits_out)
{
  constexpr int NTHR = NCG * 64;
  constexpr int NCO = COUT / NCG;     // outputs per thread (UPSHUF: incl sp)
  constexpr size_t HW = (size_t)H * W;
  __shared__ u64 s_w[COUT * 9];
  __shared__ float s_sc[COUT], s_a[COUT], s_b1[COUT], s_b2[COUT], s_mv[64];

  int t = threadIdx.x;
  for (int i = t; i < COUT * 9; i += NTHR) s_w[i] = wbits[i];
  for (int i = t; i < COUT; i += NTHR) {
    s_sc[i] = scale[i]; s_a[i] = pa[i]; s_b1[i] = pb1[i]; s_b2[i] = pb2[i];
  }
  if (t < 64) s_mv[t] = nmove[t];
  __syncthreads();

  int n = blockIdx.z;
  const u64* bin = bits_in + (size_t)n * HW;
  const float* fin = feat + (size_t)n * 64 * HW;
  float* outp = out + (size_t)n * (UPSHUF ? 256 : 64) * HW;
  u64* bop = bits_out ? bits_out + (size_t)n * (UPSHUF ? 4 : 1) * HW
                      : nullptr;

  int px = blockIdx.x * 16 + (t & 15);
  int py = blockIdx.y * 4 + ((t >> 4) & 3);
  int cg = t >> 6;                         // wave-uniform co-group
  int pix = py * W + px;

  u64 nb[9];
  int vf = 0, nvalid = 0;
#pragma unroll
  for (int ky = 0; ky < 3; ky++)
#pragma unroll
    for (int kx = 0; kx < 3; kx++) {
      int yy = py + ky - 1, xx = px + kx - 1;
      int tap = ky * 3 + kx;
      u64 m = 0;
      if (yy >= 0 && yy < H && xx >= 0 && xx < W) {
        m = bin[(size_t)yy * W + xx];
        vf |= 1 << tap; nvalid++;
      }
      nb[tap] = m;
    }
  bool interior = (vf == 511);
  int base = 64 * nvalid;

  if constexpr (!UPSHUF && !V_NHWC) {
    // ---- body path: NCHW, pack; residual loads hoisted ----
    float rv[NCO];
#pragma unroll
    for (int j = 0; j < NCO; j++)
      rv[j] = fin[(size_t)(cg * NCO + j) * HW + pix];
    u32 pk = 0;
#pragma unroll
    for (int jb = 0; jb < NCO; jb += 4) {
#pragma unroll
      for (int s = 0; s < 4; s++) {
        int j = jb + s;
        int co = cg * NCO + j;
        int c = 0;
#pragma unroll
        for (int tap = 0; tap < 9; tap++)
          c += __popcll(nb[tap] ^ s_w[co * 9 + tap]);
        if (!interior) {
#pragma unroll
          for (int tap = 0; tap < 9; tap++)
            if (!((vf >> tap) & 1)) c -= __popcll(s_w[co * 9 + tap]);
        }
        int sint = base - 2 * c;
        float conv = fmul(s_sc[co], (float)sint);
        float t1 = fadd(conv, s_b1[co]);
        float t2 = t1 >= 0.0f ? t1 : fmul(s_a[co], t1);
        float t3 = fadd(t2, s_b2[co]);
        float ov = fadd(t3, rv[j]);
        outp[(size_t)co * HW + pix] = ov;
        pk |= (u32)(fadd(ov, s_mv[co]) > 0.0f) << j;
      }
    }
    if constexpr (NCO == 16) {
      ((u16*)bop)[pix * 4 + cg] = (u16)pk;
    } else {                             // NCO == 8: byte slice per cg
      ((u8*)bop)[pix * 8 + cg] = (u8)pk;
    }
  } else if constexpr (!UPSHUF && V_NHWC) {
    // ---- hr path: NHWC residual hoisted, NHWC V out with leaky, no pack --
    float4 uv4[NCO / 4];
#pragma unroll
    for (int q = 0; q < NCO / 4; q++)
      uv4[q] = *(const float4*)(fin + (size_t)pix * 64 + cg * NCO + q * 4);
#pragma unroll
    for (int jb = 0; jb < NCO; jb += 4) {
      float us[4] = {uv4[jb >> 2].x, uv4[jb >> 2].y, uv4[jb >> 2].z,
                     uv4[jb >> 2].w};
      float vq[4];
#pragma unroll
      for (int s = 0; s < 4; s++) {
        int co = cg * NCO + jb + s;
        int c = 0;
#pragma unroll
        for (int tap = 0; tap < 9; tap++)
          c += __popcll(nb[tap] ^ s_w[co * 9 + tap]);
        if (!interior) {
#pragma unroll
          for (int tap = 0; tap < 9; tap++)
            if (!((vf >> tap) & 1)) c -= __popcll(s_w[co * 9 + tap]);
        }
        int sint = base - 2 * c;
        float conv = fmul(s_sc[co], (float)sint);
        float t1 = fadd(conv, s_b1[co]);
        float t2 = t1 >= 0.0f ? t1 : fmul(s_a[co], t1);
        float t3 = fadd(t2, s_b2[co]);
        float ov = fadd(t3, us[s]);
        vq[s] = ov >= 0.0f ? ov : fmul(0.1f, ov);      // leaky pre-applied
      }
      float4 v4 = make_float4(vq[0], vq[1], vq[2], vq[3]);
      *(float4*)(outp + (size_t)pix * 64 + cg * NCO + jb) = v4;
    }
  } else {
    // ---- up path (NCG=4): NHWC out. co = cg*64 + j, j = ((ob+k)<<2)|sp --
    u32 pk[4] = {0, 0, 0, 0};
    for (int ob = 0; ob < 16; ob += 4) {
#pragma unroll
      for (int sp = 0; sp < 4; sp++) {
        float vq[4];
#pragma unroll
        for (int k = 0; k < 4; k++) {
          int j = ((ob + k) << 2) | sp;
          int co = cg * 64 + j;
          int c = 0;
#pragma unroll
          for (int tap = 0; tap < 9; tap++)
            c += __popcll(nb[tap] ^ s_w[co * 9 + tap]);
          if (!interior) {
#pragma unroll
            for (int tap = 0; tap < 9; tap++)
              if (!((vf >> tap) & 1)) c -= __popcll(s_w[co * 9 + tap]);
          }
          int sint = base - 2 * c;
          float conv = fmul(s_sc[co], (float)sint);
          float t1 = fadd(conv, s_b1[co]);
          float t2 = t1 >= 0.0f ? t1 : fmul(s_a[co], t1);
          float t3 = fadd(t2, s_b2[co]);
          float rv = RES_NHWC ? fin[(size_t)pix * 64 + j]
                              : fin[(size_t)j * HW + pix];
          float ov = fadd(t3, rv);
          vq[k] = ov;
          pk[sp] |= (u32)(fadd(ov, s_mv[cg * 16 + ob + k]) > 0.0f)
                    << (ob + k);
        }
        int dr = sp >> 1, dc = sp & 1;
        size_t opix = (size_t)(2 * py + dr) * (2 * W) + (2 * px + dc);
        float4 v4 = make_float4(vq[0], vq[1], vq[2], vq[3]);
        *(float4*)(outp + opix * 64 + cg * 16 + ob) = v4;
      }
    }
#pragma unroll
    for (int sp = 0; sp < 4; sp++) {
      int dr = sp >> 1, dc = sp & 1;
      size_t opix = (size_t)(2 * py + dr) * (2 * W) + (2 * px + dc);
      ((u16*)bop)[opix * 4 + cg] = (u16)pk[sp];
    }
  }
}

// --- conv_last: V NHWC (512*512,64) leaky pre-applied; XCD-swizzled --------
// Grid MUST be 1024 blocks (32x32 tiles); swz bijective for nwg=1024.
__global__ __launch_bounds__(256) void conv_last_kernel(
    const float* __restrict__ V,      // (512*512,64) leaky-applied
    const float* __restrict__ w, const float* __restrict__ b,
    const float* __restrict__ x,      // (3,128,128)
    float* __restrict__ out) {        // (3,512,512)
  int t = threadIdx.x;
  // XCD-aware swizzle: consecutive bids round-robin XCDs; give XCD k the
  // contiguous tile chunk [k*128,(k+1)*128) -> 4 tile-rows, L2-resident.
  int bid = blockIdx.y * gridDim.x + blockIdx.x;
  int swz = (bid & 7) * 128 + (bid >> 3);
  int gx = (swz & 31) * 16 + (t & 15);
  int gy = (swz >> 5) * 16 + (t >> 4);
  float acc0 = 0.f, acc1 = 0.f, acc2 = 0.f;
  for (int ky = 0; ky < 3; ky++) {             // (ky,kx,ci), ci fastest
    int yy = gy + ky - 1;
    if (yy < 0 || yy > 511) continue;
    for (int kx = 0; kx < 3; kx++) {
      int xx = gx + kx - 1;
      if (xx < 0 || xx > 511) continue;
      int tap = ky * 3 + kx;
      const float4* vp = (const float4*)(V + ((size_t)(yy << 9) + xx) * 64);
#pragma unroll 4
      for (int c4 = 0; c4 < 16; c4++) {
        float4 v = vp[c4];
        int k = (c4 * 4) * 9 + tap;
        acc0 = fmaf(v.x, w[k], acc0);
        acc1 = fmaf(v.x, w[576 + k], acc1);
        acc2 = fmaf(v.x, w[1152 + k], acc2);
        acc0 = fmaf(v.y, w[k + 9], acc0);
        acc1 = fmaf(v.y, w[576 + k + 9], acc1);
        acc2 = fmaf(v.y, w[1152 + k + 9], acc2);
        acc0 = fmaf(v.z, w[k + 18], acc0);
        acc1 = fmaf(v.z, w[576 + k + 18], acc1);
        acc2 = fmaf(v.z, w[1152 + k + 18], acc2);
        acc0 = fmaf(v.w, w[k + 27], acc0);
        acc1 = fmaf(v.w, w[576 + k + 27], acc1);
        acc2 = fmaf(v.w, w[1152 + k + 27], acc2);
      }
    }
  }
  float o0 = fadd(acc0, b[0]);
  float o1 = fadd(acc1, b[1]);
  float o2 = fadd(acc2, b[2]);
  float sy = (gy + 0.5f) * 0.25f - 0.5f;
  float sx = (gx + 0.5f) * 0.25f - 0.5f;
  int iy0 = (int)floorf(sy);
  int ix0 = (int)floorf(sx);
  float fy = sy - (float)iy0, fx = sx - (float)ix0;
  int y0c = min(max(iy0, 0), 127), y1c = min(max(iy0 + 1, 0), 127);
  int x0c = min(max(ix0, 0), 127), x1c = min(max(ix0 + 1, 0), 127);
  float accs[3] = {o0, o1, o2};
#pragma unroll
  for (int co = 0; co < 3; co++) {
    const float* xp = x + (size_t)co * 16384;
    float c00 = xp[y0c * 128 + x0c], c01 = xp[y0c * 128 + x1c];
    float c10 = xp[y1c * 128 + x0c], c11 = xp[y1c * 128 + x1c];
    float v0, v1;
    if (y1c == y0c) { v0 = fmul(1.f, c00); v1 = fmul(1.f, c01); }
    else {
      v0 = fadd(fmul(1.f - fy, c00), fmul(fy, c10));
      v1 = fadd(fmul(1.f - fy, c01), fmul(fy, c11));
    }
    float base = (x1c == x0c) ? fmul(1.f, v0)
                              : fadd(fmul(1.f - fx, v0), fmul(fx, v1));
    out[((size_t)co << 18) + ((size_t)gy << 9) + gx] = fadd(accs[co], base);
  }
}

extern "C" void kernel_launch(void* const* d_in, const int* in_sizes, int n_in,
                              void* d_out, int out_size, void* d_ws,
                              size_t ws_size, hipStream_t stream) {
  const float* x         = (const float*)d_in[0];
  const float* cf_w      = (const float*)d_in[1];
  const float* cf_b      = (const float*)d_in[2];
  const float* body_move = (const float*)d_in[3];
  const float* body_w    = (const float*)d_in[4];
  const float* body_a    = (const float*)d_in[5];
  const float* body_b1   = (const float*)d_in[6];
  const float* body_b2   = (const float*)d_in[7];
  const float* up1_move  = (const float*)d_in[8];
  const float* up1_w     = (const float*)d_in[9];
  const float* up1_a     = (const float*)d_in[10];
  const float* up1_b1    = (const float*)d_in[11];
  const float* up1_b2    = (const float*)d_in[12];
  const float* up2_move  = (const float*)d_in[13];
  const float* up2_w     = (const float*)d_in[14];
  const float* up2_a     = (const float*)d_in[15];
  const float* up2_b1    = (const float*)d_in[16];
  const float* up2_b2    = (const float*)d_in[17];
  const float* hr_move   = (const float*)d_in[18];
  const float* hr_w      = (const float*)d_in[19];
  const float* hr_a      = (const float*)d_in[20];
  const float* hr_b1     = (const float*)d_in[21];
  const float* hr_b2     = (const float*)d_in[22];
  const float* cl_w      = (const float*)d_in[23];
  const float* cl_b      = (const float*)d_in[24];
  float* out = (float*)d_out;

  const size_t M = 1024 * 1024;
  if (ws_size < 160 * M) {
    diag_kernel<<<(out_size + 255) / 256, 256, 0, stream>>>(
        out, out_size, (float)(ws_size >> 20));
    return;
  }

  char* ws = (char*)d_ws;
  float* A    = (float*)(ws + 0);          // (4,64,128,128) NCHW, 16M
  float* B    = (float*)(ws + 16 * M);     // body pong (dead before up1)
  float* Pbat = (float*)(ws + 16 * M);     // (4,256*256,64) NHWC, 64M
  float* U    = (float*)(ws + 80 * M);     // (512*512,64) NHWC per-sample;
                                           //   hr writes V in-place here
  u64* bitsA   = (u64*)(ws + 144 * M);     // (4,16384) 512K
  u64* bitsB   = (u64*)(ws + 144 * M + 512 * 1024);
  u64* bits256 = (u64*)(ws + 145 * M);     // (4,65536) 2M
  u64* bits512 = (u64*)(ws + 147 * M);     // (512*512) 2M per-sample
  u64* wbits   = (u64*)(ws + 149 * M);     // 2624*9 u64
  float* scales = (float*)(ws + 150 * M);  // 2624 f32

  // weight prep
  binw_pack_kernel<<<32, 64, 0, stream>>>(body_w, wbits, scales, 2048);
  binw_pack_kernel<<<4, 64, 0, stream>>>(up1_w, wbits + (size_t)2048 * 9,
                                         scales + 2048, 256);
  binw_pack_kernel<<<4, 64, 0, stream>>>(up2_w, wbits + (size_t)2304 * 9,
                                         scales + 2304, 256);
  binw_pack_kernel<<<1, 64, 0, stream>>>(hr_w, wbits + (size_t)2560 * 9,
                                         scales + 2560, 64);

  // head (all samples batched)
  conv_first_kernel<<<dim3(4096, 4), 256, 0, stream>>>(x, cf_w, cf_b, A);
  pack_kernel<<<dim3(64, 4), 256, 0, stream>>>(A, body_move, bitsA);

  // body: 32 BBCU layers, batched over samples; 512-thr / 8-wave blocks
  float* fin = A;
  float* fout = B;
  u64* bbin = bitsA;
  u64* bbout = bitsB;
  for (int u = 0; u < 32; u++) {
    const float* nm = (u < 31) ? body_move + (u + 1) * 64 : up1_move;
    bconv_kernel<128, 128, 64, false, false, false, 8>
        <<<dim3(8, 32, 4), 512, 0, stream>>>(
            bbin, fin, wbits + (size_t)u * 576, scales + u * 64,
            body_a + u * 64, body_b1 + u * 64, body_b2 + u * 64, nm,
            fout, bbout);
    float* tf = fin; fin = fout; fout = tf;
    u64* tb = bbin; bbin = bbout; bbout = tb;
  }
  // body out in A (even swap count), its bits (packed w/ up1_move) in bitsA

  // up1 batched: NCHW res A -> NHWC Pbat; bits (w/ up2_move) in bits256
  bconv_kernel<128, 128, 256, true, false, false, 4>
      <<<dim3(8, 32, 4), 256, 0, stream>>>(
          bitsA, A, wbits + (size_t)2048 * 9, scales + 2048,
          up1_a, up1_b1, up1_b2, up2_move, Pbat, bits256);

  // per sample: up2 -> hr (in-place V over U) -> conv_last
  for (int n = 0; n < 4; n++) {
    // up2: NHWC res P[n] -> NHWC U; bits (w/ hr_move) in bits512
    bconv_kernel<256, 256, 256, true, true, false, 4>
        <<<dim3(16, 64, 1), 256, 0, stream>>>(
            bits256 + (size_t)n * 65536, Pbat + (size_t)n * 4194304,
            wbits + (size_t)2304 * 9, scales + 2304,
            up2_a, up2_b1, up2_b2, hr_move, U, bits512);
    // hr: NHWC U residual -> V NHWC leaky pre-applied, IN-PLACE over U
    bconv_kernel<512, 512, 64, false, true, true, 8>
        <<<dim3(32, 128, 1), 512, 0, stream>>>(
            bits512, U, wbits + (size_t)2560 * 9, scales + 2560,
            hr_a, hr_b1, hr_b2, hr_move, U, nullptr);
    // conv_last + bilinear base (16x16 tiles, XCD swizzle)
    conv_last_kernel<<<dim3(32, 32), 256, 0, stream>>>(
        U, cl_w, cl_b, x + (size_t)n * 49152,
        out + (size_t)n * 786432);
  }
}